// Round 14
// baseline (356.334 us; speedup 1.0000x reference)
//
#include <hip/hip_runtime.h>
#include <math.h>

#define NB 1024
#define C1 16
#define H1 4
#define W1 153
#define WX 216
#define K1 64
#define C2 32
#define H2 4
#define W2 155
#define W192 192
#define PW2 38
#define C3 32
#define W3 38

typedef short short4v __attribute__((ext_vector_type(4)));
typedef short short8 __attribute__((ext_vector_type(8)));
typedef float f32x16 __attribute__((ext_vector_type(16)));

// ---- workspace float offsets
#define OFF_OUT1     0
#define OFF_A1H      10027008
#define OFF_A1L      16318464
#define OFF_W2PH     22609920
#define OFF_W2PL     22626304
#define OFF_W3PH     22642688
#define OFF_W3PL     22659072
#define OFF_UH       22675456
#define OFF_UL       22806528
#define OFF_POOL2RAW 22937600
#define OFF_A2H      25427968
#define OFF_A2L      27787264
#define OFF_FEATSRAW 30146560
#define OFF_QO       30441472
#define OFF_PART1    30736384
#define OFF_PART2    30867456
#define OFF_PART3    30998528
#define OFF_STATS1   31031296
#define OFF_STATS2   31031328
#define OFF_STATS3   31031392

__device__ __forceinline__ float eluf(float x){ return x > 0.f ? x : expm1f(x); }

__device__ __forceinline__ ushort bf16h(float x){
  unsigned u = __float_as_uint(x);
  unsigned r = u + 0x7fffu + ((u >> 16) & 1u);
  return (ushort)(r >> 16);
}
__device__ __forceinline__ float bf16f(ushort h){ return __uint_as_float(((unsigned)h) << 16); }

__device__ __forceinline__ short8 cat8(short4v a, short4v b){
  return __builtin_shufflevector(a, b, 0,1,2,3,4,5,6,7);
}

// ---------------- conv1 + fused BN stats partial
__global__ __launch_bounds__(256) void k_conv1s(const float* __restrict__ x,
                                                const float* __restrict__ w1,
                                                float* __restrict__ out1,
                                                float* __restrict__ part1){
  __shared__ float xr[4][WX];
  __shared__ float wl[C1*K1];
  int n = blockIdx.x, tid = threadIdx.x;
  for (int i = tid; i < 4*WX; i += 256) xr[i/WX][i%WX] = x[(size_t)n*4*WX + i];
  for (int i = tid; i < C1*K1; i += 256) wl[i] = w1[i];
  __syncthreads();
  int h = tid >> 6, lane = tid & 63;
  float acc[16][3];
  #pragma unroll
  for (int c = 0; c < 16; ++c){ acc[c][0]=0.f; acc[c][1]=0.f; acc[c][2]=0.f; }
  bool v2 = (lane + 128) < W1;
  for (int k = 0; k < 64; ++k){
    float x0 = xr[h][lane + k];
    float x1 = xr[h][lane + 64 + k];
    float x2 = v2 ? xr[h][lane + 128 + k] : 0.f;
    #pragma unroll
    for (int c = 0; c < 16; ++c){
      float wk = wl[c*64 + k];
      acc[c][0] += wk*x0; acc[c][1] += wk*x1; acc[c][2] += wk*x2;
    }
  }
  float ss[16], sq[16];
  #pragma unroll
  for (int c = 0; c < 16; ++c){
    float* ob = out1 + (((size_t)(n*16 + c)*4 + h))*W1;
    ob[lane] = acc[c][0];
    ob[lane + 64] = acc[c][1];
    if (v2) ob[lane + 128] = acc[c][2];
    ss[c] = acc[c][0] + acc[c][1] + acc[c][2];
    sq[c] = acc[c][0]*acc[c][0] + acc[c][1]*acc[c][1] + acc[c][2]*acc[c][2];
  }
  #pragma unroll
  for (int m = 1; m < 64; m <<= 1){
    #pragma unroll
    for (int c = 0; c < 16; ++c){ ss[c] += __shfl_xor(ss[c], m); sq[c] += __shfl_xor(sq[c], m); }
  }
  if (lane == 0){
    #pragma unroll
    for (int c = 0; c < 16; ++c){
      part1[((size_t)(n*4 + h)*16 + c)*2]     = ss[c];
      part1[((size_t)(n*4 + h)*16 + c)*2 + 1] = sq[c];
    }
  }
}

// ---------------- parallel stats finalize: grid = C blocks
__global__ __launch_bounds__(256) void k_stats_finP(const float* __restrict__ part,
                                                    float* __restrict__ stats,
                                                    int C, int nblk, float inv){
  __shared__ float rs[256], rq[256];
  int c = blockIdx.x;
  float s = 0.f, q = 0.f;
  for (int b = threadIdx.x; b < nblk; b += 256){
    s += part[((size_t)b*C + c)*2];
    q += part[((size_t)b*C + c)*2 + 1];
  }
  rs[threadIdx.x] = s; rq[threadIdx.x] = q; __syncthreads();
  for (int st = 128; st > 0; st >>= 1){
    if (threadIdx.x < st){ rs[threadIdx.x] += rs[threadIdx.x+st]; rq[threadIdx.x] += rq[threadIdx.x+st]; }
    __syncthreads();
  }
  if (threadIdx.x == 0){
    float mean = rs[0]*inv;
    float var  = rq[0]*inv - mean*mean;
    stats[c*2]   = mean;
    stats[c*2+1] = rsqrtf(var + 1e-5f);
  }
}

// ---------------- bnelu1: LDS-staged coalesced. block=(n,h). 4-granular 2-bit ci swizzle.
__global__ __launch_bounds__(256) void k_bnelu1(const float* __restrict__ out1,
                                                const float* __restrict__ stats,
                                                ushort* __restrict__ a1h, ushort* __restrict__ a1l){
  __shared__ float xf[2448];   // 16ci x 153w
  __shared__ float st[32];
  int b = blockIdx.x;          // = n*4 + h
  int n = b >> 2, h = b & 3;
  int tid = threadIdx.x;
  if (tid < 32) st[tid] = stats[tid];
  for (int i = tid; i < 2448; i += 256){
    int ci = i / 153, w = i - ci*153;
    xf[i] = out1[((size_t)(n*16 + ci)*4 + h)*W1 + w];
  }
  __syncthreads();
  for (int i = tid; i < 3072; i += 256){
    int w = i >> 4, ci = i & 15;
    float v = 0.f;
    int ws = w - 16;
    if ((unsigned)ws < (unsigned)W1){
      float xx = xf[ci*153 + ws];
      v = eluf((xx - st[ci*2])*st[ci*2+1]);
    }
    int ciS = ci ^ (((w >> 2) & 3) << 2);   // matches conv2f b64-pair reads
    size_t o = (size_t)b*3072 + w*16 + ciS;
    ushort hs = bf16h(v);
    a1h[o] = hs;
    a1l[o] = bf16h(v - bf16f(hs));
  }
}

// ---------------- weight convert+permute
__global__ void k_cvtw(const float* __restrict__ w2, const float* __restrict__ w3,
                       ushort* __restrict__ w2ph, ushort* __restrict__ w2pl,
                       ushort* __restrict__ w3ph, ushort* __restrict__ w3pl){
  int idx = blockIdx.x*256 + threadIdx.x;
  if (idx < 32768){
    int ci = idx & 15; int co = (idx >> 4) & 31; int rk = idx >> 9;
    int r = rk >> 5, kw = rk & 31;
    float v = w2[((size_t)(co*16 + ci)*2 + r)*32 + kw];
    ushort hs = bf16h(v); float hf = bf16f(hs);
    w2ph[idx] = hs; w2pl[idx] = bf16h(v - hf);
  } else {
    int j = idx - 32768;
    int ci = j & 31; int co = (j >> 5) & 31; int rk = j >> 10;
    int r = rk >> 2, kw = rk & 3;
    float v = w3[((size_t)(co*32 + ci)*8 + r)*4 + kw];
    ushort hs = bf16h(v); float hf = bf16f(hs);
    w3ph[j] = hs; w3pl[j] = bf16h(v - hf);
  }
}

// ---------------- fused conv2 v8b: 320-thread blocks, 5 waves = 5 position frags,
// one frag per wave (acc = 2x16 = 32 VGPR). launch_bounds(320,4): VGPR cap 128
// => no spill (needs ~90); LDS 38.4KB still allows 4 blocks/CU = 20 waves resident.
template<int HG>
__global__ __launch_bounds__(320, 4) void k_conv2f5(const ushort* __restrict__ a1h,
                                                    const ushort* __restrict__ a1l,
                                                    const ushort* __restrict__ w2ph,
                                                    const ushort* __restrict__ w2pl,
                                                    float* __restrict__ pool2raw,
                                                    float* __restrict__ part2){
  constexpr int NR = HG ? 2 : 3;
  __shared__ __align__(16) ushort s_hi[NR*3072];
  __shared__ __align__(16) ushort s_lo[NR*3072];
  __shared__ float statW[5][32][2];
  int n = blockIdx.x;
  int tid = threadIdx.x;
  {
    const float4* gh = (const float4*)(a1h + ((size_t)n*4 + 2*HG)*3072);
    const float4* gl = (const float4*)(a1l + ((size_t)n*4 + 2*HG)*3072);
    float4* dh = (float4*)s_hi;
    float4* dl = (float4*)s_lo;
    for (int i = tid; i < NR*384; i += 320){ dh[i] = gh[i]; dl[i] = gl[i]; }
  }
  __syncthreads();
  int wave = tid >> 6, lane = tid & 63;
  int l5 = lane >> 5, l31 = lane & 31;
  int p = wave + (n % 5); p = (p >= 5) ? p - 5 : p;   // role permute, bijective
  int e4 = l5*4;

  f32x16 acc0, acc1;
  #pragma unroll
  for (int e = 0; e < 16; ++e){ acc0[e] = 0.f; acc1[e] = 0.f; }

  for (int kw = 0; kw < 32; ++kw){
    // A fragments (global, L2-resident)
    short8 Ah[2], Al[2];
    #pragma unroll
    for (int r = 0; r < 2; ++r){
      int widx = ((r*32 + kw)*32 + l31)*16 + e4;
      Ah[r] = cat8(*(const short4v*)(w2ph + widx), *(const short4v*)(w2ph + widx + 8));
      Al[r] = cat8(*(const short4v*)(w2pl + widx), *(const short4v*)(w2pl + widx + 8));
    }
    // B fragments: this wave's frag p, all NR rows
    short8 bh[NR], bl[NR];
    int pos = p*32 + l31 + kw;
    int sw = ((pos >> 2) & 3) << 2;
    int o0 = pos*16 + (e4 ^ sw);
    #pragma unroll
    for (int j = 0; j < NR; ++j){
      int off = j*3072 + o0;
      bh[j] = cat8(*(const short4v*)(s_hi + off), *(const short4v*)(s_hi + (off ^ 8)));
      bl[j] = cat8(*(const short4v*)(s_lo + off), *(const short4v*)(s_lo + (off ^ 8)));
    }
    // lh=0: r=0 -> j0, r=1 -> j1 ; lh=1: r=0 -> j1, r=1 -> j2 (NR==3 only)
    acc0 = __builtin_amdgcn_mfma_f32_32x32x16_bf16(Ah[0], bh[0], acc0, 0, 0, 0);
    acc0 = __builtin_amdgcn_mfma_f32_32x32x16_bf16(Ah[0], bl[0], acc0, 0, 0, 0);
    acc0 = __builtin_amdgcn_mfma_f32_32x32x16_bf16(Al[0], bh[0], acc0, 0, 0, 0);
    acc0 = __builtin_amdgcn_mfma_f32_32x32x16_bf16(Ah[1], bh[1], acc0, 0, 0, 0);
    acc0 = __builtin_amdgcn_mfma_f32_32x32x16_bf16(Ah[1], bl[1], acc0, 0, 0, 0);
    acc0 = __builtin_amdgcn_mfma_f32_32x32x16_bf16(Al[1], bh[1], acc0, 0, 0, 0);
    acc1 = __builtin_amdgcn_mfma_f32_32x32x16_bf16(Ah[0], bh[1], acc1, 0, 0, 0);
    acc1 = __builtin_amdgcn_mfma_f32_32x32x16_bf16(Ah[0], bl[1], acc1, 0, 0, 0);
    acc1 = __builtin_amdgcn_mfma_f32_32x32x16_bf16(Al[0], bh[1], acc1, 0, 0, 0);
    if constexpr (NR == 3){
      acc1 = __builtin_amdgcn_mfma_f32_32x32x16_bf16(Ah[1], bh[2], acc1, 0, 0, 0);
      acc1 = __builtin_amdgcn_mfma_f32_32x32x16_bf16(Ah[1], bl[2], acc1, 0, 0, 0);
      acc1 = __builtin_amdgcn_mfma_f32_32x32x16_bf16(Al[1], bh[2], acc1, 0, 0, 0);
    }
  }

  // ---- stats partial (mask pos>=155); C/D map col=l31, row co=(e&3)+8*(e>>2)+4*l5
  {
    float sreg[16], qreg[16];
    bool pv = (p < 4) || (l31 < 27);
    #pragma unroll
    for (int e = 0; e < 16; ++e){
      float v0 = pv ? acc0[e] : 0.f;
      float v1 = pv ? acc1[e] : 0.f;
      sreg[e] = v0 + v1;
      qreg[e] = v0*v0 + v1*v1;
    }
    #pragma unroll
    for (int m = 1; m < 32; m <<= 1){
      #pragma unroll
      for (int e = 0; e < 16; ++e){
        sreg[e] += __shfl_xor(sreg[e], m);
        qreg[e] += __shfl_xor(qreg[e], m);
      }
    }
    if (l31 == 0){
      #pragma unroll
      for (int e = 0; e < 16; ++e){
        int co = (e & 3) + ((e >> 2) << 3) + (l5 << 2);
        statW[p][co][0] = sreg[e];
        statW[p][co][1] = qreg[e];
      }
    }
  }
  // ---- in-register cross-h max + quad pool, direct global write
  #pragma unroll
  for (int e = 0; e < 16; ++e){
    float m0 = fmaxf(acc0[e], acc1[e]);
    float v1 = fmaxf(m0, __shfl_xor(m0, 1));
    float v2m = fmaxf(v1, __shfl_xor(v1, 2));
    int pw = p*8 + (l31 >> 2);
    if ((l31 & 3) == 0 && pw < PW2){
      int co = (e & 3) + ((e >> 2) << 3) + (l5 << 2);
      pool2raw[(((size_t)n*2 + HG)*32 + co)*PW2 + pw] = v2m;
    }
  }
  __syncthreads();
  if (tid < 32){
    float s = statW[0][tid][0] + statW[1][tid][0] + statW[2][tid][0] + statW[3][tid][0] + statW[4][tid][0];
    float q = statW[0][tid][1] + statW[1][tid][1] + statW[2][tid][1] + statW[3][tid][1] + statW[4][tid][1];
    part2[(((size_t)n*2 + HG)*32 + tid)*2]     = s;
    part2[(((size_t)n*2 + HG)*32 + tid)*2 + 1] = q;
  }
}

// ---------------- bn2: LDS-staged coalesced. block=(n,hr)
__global__ __launch_bounds__(256) void k_bn2(const float* __restrict__ pool2raw,
                                             const float* __restrict__ stats,
                                             ushort* __restrict__ a2h, ushort* __restrict__ a2l){
  __shared__ float xf[1216];   // 32ci x 38pw
  __shared__ float st[64];
  int b = blockIdx.x;          // = n*2 + hr, 2048
  int tid = threadIdx.x;
  if (tid < 64) st[tid] = stats[tid];
  for (int i = tid; i < 1216; i += 256) xf[i] = pool2raw[(size_t)b*1216 + i];
  __syncthreads();
  for (int i = tid; i < 2304; i += 256){
    int w = i >> 5, ci = i & 31;
    float v = 0.f;
    int pw = w - 2;
    if ((unsigned)pw < (unsigned)PW2)
      v = eluf((xf[ci*38 + pw] - st[ci*2])*st[ci*2+1]);
    int ciS = ci ^ (((w >> 1) & 7) << 2);
    size_t o = (size_t)b*2304 + w*32 + ciS;
    ushort hs = bf16h(v);
    a2h[o] = hs; a2l[o] = bf16h(v - bf16f(hs));
  }
}

// ---------------- fused conv3 (MFMA 3-term bf16) + stats partial + maxpool(2,4)
__global__ __launch_bounds__(256, 2) void k_conv3f(const ushort* __restrict__ a2h,
                                                   const ushort* __restrict__ a2l,
                                                   const ushort* __restrict__ w3ph,
                                                   const ushort* __restrict__ w3pl,
                                                   float* __restrict__ featsraw,
                                                   float* __restrict__ part3){
  __shared__ __align__(16) ushort s3h[9216];
  __shared__ __align__(16) ushort s3l[9216];
  __shared__ float poolL3[4][32][12];
  __shared__ float statL3[4][32][2];
  int nb = blockIdx.x;
  int tid = threadIdx.x;
  {
    const float4* gh = (const float4*)(a2h + (size_t)nb*9216);
    const float4* gl = (const float4*)(a2l + (size_t)nb*9216);
    float4* dh = (float4*)s3h;
    float4* dl = (float4*)s3l;
    for (int i = tid; i < 1152; i += 256){ dh[i] = gh[i]; dl[i] = gl[i]; }
  }
  __syncthreads();
  int wave = tid >> 6, lane = tid & 63;
  int nh = wave >> 1, h = wave & 1;
  int l5 = lane >> 5, l31 = lane & 31;

  f32x16 acc[2];
  #pragma unroll
  for (int p = 0; p < 2; ++p)
    #pragma unroll
    for (int e = 0; e < 16; ++e) acc[p][e] = 0.f;

  #pragma unroll
  for (int ri = 0; ri < 2; ++ri){
    int r = (h == 0) ? (4 + ri) : (3 + ri);
    int rbase = (nh*2 + ri)*72*32;
    #pragma unroll
    for (int kw = 0; kw < 4; ++kw){
      #pragma unroll
      for (int ch = 0; ch < 2; ++ch){
        int widx = ((r*4 + kw)*32 + l31)*32 + ch*16 + l5*4;
        short8 Ah = cat8(*(const short4v*)(w3ph + widx), *(const short4v*)(w3ph + widx + 8));
        short8 Al = cat8(*(const short4v*)(w3pl + widx), *(const short4v*)(w3pl + widx + 8));
        short8 Bh[2], Bl[2];
        #pragma unroll
        for (int p = 0; p < 2; ++p){
          int pos = p*32 + l31 + kw;
          int sw = ((pos >> 1) & 7) << 2;
          int s0 = ch*16 + l5*4;
          int off0 = rbase + pos*32 + (s0 ^ sw);
          int off1 = rbase + pos*32 + ((s0 + 8) ^ sw);
          Bh[p] = cat8(*(const short4v*)(s3h + off0), *(const short4v*)(s3h + off1));
          Bl[p] = cat8(*(const short4v*)(s3l + off0), *(const short4v*)(s3l + off1));
        }
        #pragma unroll
        for (int p = 0; p < 2; ++p) acc[p] = __builtin_amdgcn_mfma_f32_32x32x16_bf16(Ah, Bh[p], acc[p], 0, 0, 0);
        #pragma unroll
        for (int p = 0; p < 2; ++p) acc[p] = __builtin_amdgcn_mfma_f32_32x32x16_bf16(Ah, Bl[p], acc[p], 0, 0, 0);
        #pragma unroll
        for (int p = 0; p < 2; ++p) acc[p] = __builtin_amdgcn_mfma_f32_32x32x16_bf16(Al, Bh[p], acc[p], 0, 0, 0);
      }
    }
  }

  {
    float sreg[16], qreg[16];
    #pragma unroll
    for (int e = 0; e < 16; ++e){ sreg[e] = 0.f; qreg[e] = 0.f; }
    #pragma unroll
    for (int p = 0; p < 2; ++p){
      bool pv = (p == 0) || (l31 < 6);
      #pragma unroll
      for (int e = 0; e < 16; ++e){
        float v = pv ? acc[p][e] : 0.f;
        sreg[e] += v; qreg[e] += v*v;
      }
    }
    #pragma unroll
    for (int m = 1; m < 32; m <<= 1){
      #pragma unroll
      for (int e = 0; e < 16; ++e){
        sreg[e] += __shfl_xor(sreg[e], m);
        qreg[e] += __shfl_xor(qreg[e], m);
      }
    }
    if (l31 == 0){
      #pragma unroll
      for (int e = 0; e < 16; ++e){
        int co = (e & 3) + ((e >> 2) << 3) + (l5 << 2);
        statL3[wave][co][0] = sreg[e];
        statL3[wave][co][1] = qreg[e];
      }
    }
  }
  #pragma unroll
  for (int p = 0; p < 2; ++p){
    #pragma unroll
    for (int e = 0; e < 16; ++e){
      float v = acc[p][e];
      float v1 = fmaxf(v, __shfl_xor(v, 1));
      float v2m = fmaxf(v1, __shfl_xor(v1, 2));
      int pw = p*8 + (l31 >> 2);
      if ((l31 & 3) == 0 && pw < 9){
        int co = (e & 3) + ((e >> 2) << 3) + (l5 << 2);
        poolL3[wave][co][pw] = v2m;
      }
    }
  }
  __syncthreads();
  for (int i = tid; i < 2*32*9; i += 256){
    int pw = i % 9; int t = i / 9; int co = t & 31; int nh2 = t >> 5;
    float v = fmaxf(poolL3[nh2*2][co][pw], poolL3[nh2*2+1][co][pw]);
    featsraw[((size_t)(nb*2 + nh2)*32 + co)*9 + pw] = v;
  }
  if (tid < 32){
    float s = 0.f, q = 0.f;
    #pragma unroll
    for (int wv = 0; wv < 4; ++wv){ s += statL3[wv][tid][0]; q += statL3[wv][tid][1]; }
    part3[((size_t)nb*32 + tid)*2]     = s;
    part3[((size_t)nb*32 + tid)*2 + 1] = q;
  }
}

// ---------------- build U (512x512) by running the fixed circuit on basis states
__global__ __launch_bounds__(256) void k_buildU(const float* __restrict__ qw,
                                                ushort* __restrict__ Uh, ushort* __restrict__ Ul){
  __shared__ float wt[36][2];
  int tid = threadIdx.x;
  if (tid < 36){ float s, c; sincosf(qw[tid]*0.5f, &s, &c); wt[tid][0] = c; wt[tid][1] = s; }
  __syncthreads();
  int wid = tid >> 6, lane = tid & 63;
  int k = blockIdx.x*4 + wid;
  float v[8];
  #pragma unroll
  for (int r = 0; r < 8; ++r) v[r] = (lane*8 + r == k) ? 1.f : 0.f;

  for (int j = 0; j < 4; ++j){
    #pragma unroll
    for (int i = 0; i < 5; ++i){
      int cm = 32>>i, tm = 16>>i;
      bool flip = (lane & cm) != 0;
      #pragma unroll
      for (int r = 0; r < 8; ++r){
        float w = __shfl_xor(v[r], tm);
        v[r] = flip ? w : v[r];
      }
    }
    { bool flip = (lane & 1) != 0;
      #pragma unroll
      for (int r = 0; r < 4; ++r){ float a = v[r], bb = v[r+4]; v[r] = flip?bb:a; v[r+4] = flip?a:bb; } }
    { float t = v[4]; v[4] = v[6]; v[6] = t; t = v[5]; v[5] = v[7]; v[7] = t; }
    { float t = v[2]; v[2] = v[3]; v[3] = t; t = v[6]; v[6] = v[7]; v[7] = t; }
    #pragma unroll
    for (int r = 1; r < 8; r += 2) v[r] = __shfl_xor(v[r], 32);

    #pragma unroll
    for (int i = 0; i < 6; ++i){
      float c = wt[j*9+i][0], s = wt[j*9+i][1];
      int m = 32>>i;
      float sg = (lane & m) ? s : -s;
      #pragma unroll
      for (int r = 0; r < 8; ++r){
        float w = __shfl_xor(v[r], m);
        v[r] = c*v[r] + sg*w;
      }
    }
    { float c = wt[j*9+6][0], s = wt[j*9+6][1];
      #pragma unroll
      for (int r = 0; r < 4; ++r){ float a = v[r], bb = v[r+4]; v[r] = c*a - s*bb; v[r+4] = s*a + c*bb; } }
    { float c = wt[j*9+7][0], s = wt[j*9+7][1]; float a, bb;
      a=v[0]; bb=v[2]; v[0]=c*a-s*bb; v[2]=s*a+c*bb;
      a=v[1]; bb=v[3]; v[1]=c*a-s*bb; v[3]=s*a+c*bb;
      a=v[4]; bb=v[6]; v[4]=c*a-s*bb; v[6]=s*a+c*bb;
      a=v[5]; bb=v[7]; v[5]=c*a-s*bb; v[7]=s*a+c*bb; }
    { float c = wt[j*9+8][0], s = wt[j*9+8][1]; float a, bb;
      a=v[0]; bb=v[1]; v[0]=c*a-s*bb; v[1]=s*a+c*bb;
      a=v[2]; bb=v[3]; v[2]=c*a-s*bb; v[3]=s*a+c*bb;
      a=v[4]; bb=v[5]; v[4]=c*a-s*bb; v[5]=s*a+c*bb;
      a=v[6]; bb=v[7]; v[6]=c*a-s*bb; v[7]=s*a+c*bb; }
  }
  #pragma unroll
  for (int r = 0; r < 8; ++r){
    int s = lane*8 + r;
    int mf = s >> 5, r31 = s & 31;
    int addr = (((k >> 4)*16 + mf)*32 + r31)*16 + (k & 15);
    float f = v[r];
    ushort hi = bf16h(f);
    Uh[addr] = hi;
    Ul[addr] = bf16h(f - bf16f(hi));
  }
}

// ---------------- quantum GEMM v1: 64 samples/block, fused BN+ELU + <Z> epilogue
__global__ __launch_bounds__(256, 1) void k_qgemm(const float* __restrict__ featsraw,
                                                  const float* __restrict__ stats,
                                                  const ushort* __restrict__ Uh,
                                                  const ushort* __restrict__ Ul,
                                                  float* __restrict__ qo){
  __shared__ __align__(16) ushort BhL[32768];
  __shared__ __align__(16) ushort BlL[32768];
  __shared__ float angL[576];
  __shared__ float zred[4][64][9];
  int nb = blockIdx.x;
  int tid = threadIdx.x;
  for (int t = tid; t < 576; t += 256){
    float vr = featsraw[(size_t)nb*576 + t];
    int c = (t/9) & 31;
    angL[t] = 0.5f * eluf((vr - stats[c*2])*stats[c*2+1]);
  }
  __syncthreads();
  {
    int sm = tid >> 2, q = tid & 3;
    float tc[9], ts[9];
    #pragma unroll
    for (int i = 0; i < 9; ++i) sincosf(angL[sm*9 + i], &ts[i], &tc[i]);
    float Pc = ((q & 2) ? ts[0] : tc[0]) * ((q & 1) ? ts[1] : tc[1]);
    int swz = (sm >> 2) & 3;
    short4v* bh4 = (short4v*)BhL;
    short4v* bl4 = (short4v*)BlL;
    int j = 0;
    #pragma unroll
    for (int b2 = 0; b2 < 2; ++b2){ float p2 = Pc*(b2 ? ts[2] : tc[2]);
    #pragma unroll
    for (int b3 = 0; b3 < 2; ++b3){ float p3 = p2*(b3 ? ts[3] : tc[3]);
    #pragma unroll
    for (int b4 = 0; b4 < 2; ++b4){ float p4 = p3*(b4 ? ts[4] : tc[4]);
    #pragma unroll
    for (int b5 = 0; b5 < 2; ++b5){ float p5 = p4*(b5 ? ts[5] : tc[5]);
    #pragma unroll
    for (int b6 = 0; b6 < 2; ++b6){ float p6 = p5*(b6 ? ts[6] : tc[6]);
      float a0 = p6*tc[7]*tc[8];
      float a1 = p6*tc[7]*ts[8];
      float a2 = p6*ts[7]*tc[8];
      float a3 = p6*ts[7]*ts[8];
      ushort h0 = bf16h(a0), h1 = bf16h(a1), h2 = bf16h(a2), h3 = bf16h(a3);
      short4v hv; hv[0]=(short)h0; hv[1]=(short)h1; hv[2]=(short)h2; hv[3]=(short)h3;
      short4v lv; lv[0]=(short)bf16h(a0 - bf16f(h0)); lv[1]=(short)bf16h(a1 - bf16f(h1));
                  lv[2]=(short)bf16h(a2 - bf16f(h2)); lv[3]=(short)bf16h(a3 - bf16f(h3));
      int kk = q*128 + j;
      int kstep = kk >> 4;
      int g = (kk >> 2) & 3;
      int idx4 = (kstep*64 + sm)*4 + (g ^ swz);
      bh4[idx4] = hv; bl4[idx4] = lv;
      j += 4;
    }}}}}
  }
  __syncthreads();
  int wv = tid >> 6, lane = tid & 63, l5 = lane >> 5, l31 = lane & 31;
  f32x16 acc[4][2];
  #pragma unroll
  for (int jj = 0; jj < 4; ++jj)
    #pragma unroll
    for (int nf = 0; nf < 2; ++nf)
      #pragma unroll
      for (int e = 0; e < 16; ++e) acc[jj][nf][e] = 0.f;

  for (int kstep = 0; kstep < 32; ++kstep){
    short8 Bh[2], Bl[2];
    #pragma unroll
    for (int nf = 0; nf < 2; ++nf){
      int sm = nf*32 + l31;
      int base = (kstep*64 + sm)*16;
      int sz = ((sm >> 2) & 3) << 2;
      int e0 = (l5*4) ^ sz;
      int e1 = (l5*4 + 8) ^ sz;
      Bh[nf] = cat8(*(const short4v*)(BhL + base + e0), *(const short4v*)(BhL + base + e1));
      Bl[nf] = cat8(*(const short4v*)(BlL + base + e0), *(const short4v*)(BlL + base + e1));
    }
    #pragma unroll
    for (int jj = 0; jj < 4; ++jj){
      int mf = wv*4 + jj;
      const ushort* ah = Uh + ((kstep*16 + mf)*32 + l31)*16 + l5*4;
      const ushort* al = Ul + ((kstep*16 + mf)*32 + l31)*16 + l5*4;
      short8 Ah = cat8(*(const short4v*)ah, *(const short4v*)(ah + 8));
      short8 Al = cat8(*(const short4v*)al, *(const short4v*)(al + 8));
      acc[jj][0] = __builtin_amdgcn_mfma_f32_32x32x16_bf16(Ah, Bh[0], acc[jj][0], 0, 0, 0);
      acc[jj][1] = __builtin_amdgcn_mfma_f32_32x32x16_bf16(Ah, Bh[1], acc[jj][1], 0, 0, 0);
      acc[jj][0] = __builtin_amdgcn_mfma_f32_32x32x16_bf16(Ah, Bl[0], acc[jj][0], 0, 0, 0);
      acc[jj][1] = __builtin_amdgcn_mfma_f32_32x32x16_bf16(Ah, Bl[1], acc[jj][1], 0, 0, 0);
      acc[jj][0] = __builtin_amdgcn_mfma_f32_32x32x16_bf16(Al, Bh[0], acc[jj][0], 0, 0, 0);
      acc[jj][1] = __builtin_amdgcn_mfma_f32_32x32x16_bf16(Al, Bh[1], acc[jj][1], 0, 0, 0);
    }
  }
  float zz[2][9];
  #pragma unroll
  for (int nf = 0; nf < 2; ++nf)
    #pragma unroll
    for (int i = 0; i < 9; ++i) zz[nf][i] = 0.f;
  #pragma unroll
  for (int jj = 0; jj < 4; ++jj){
    int mf = wv*4 + jj;
    float sg0 = (mf & 8) ? -1.f : 1.f;
    float sg1 = (mf & 4) ? -1.f : 1.f;
    float sg2 = (mf & 2) ? -1.f : 1.f;
    float sg3 = (mf & 1) ? -1.f : 1.f;
    #pragma unroll
    for (int nf = 0; nf < 2; ++nf){
      float psum = 0.f, z4 = 0.f, z5 = 0.f, z7 = 0.f, z8 = 0.f;
      #pragma unroll
      for (int e = 0; e < 16; ++e){
        float qv = acc[jj][nf][e]*acc[jj][nf][e];
        psum += qv;
        z4 += ((e >> 3) & 1) ? -qv : qv;
        z5 += ((e >> 2) & 1) ? -qv : qv;
        z7 += ((e >> 1) & 1) ? -qv : qv;
        z8 += (e & 1) ? -qv : qv;
      }
      zz[nf][0] += sg0*psum; zz[nf][1] += sg1*psum;
      zz[nf][2] += sg2*psum; zz[nf][3] += sg3*psum;
      zz[nf][4] += z4; zz[nf][5] += z5;
      zz[nf][6] += l5 ? -psum : psum;
      zz[nf][7] += z7; zz[nf][8] += z8;
    }
  }
  #pragma unroll
  for (int nf = 0; nf < 2; ++nf)
    #pragma unroll
    for (int i = 0; i < 9; ++i) zz[nf][i] += __shfl_xor(zz[nf][i], 32);
  if (l5 == 0){
    #pragma unroll
    for (int nf = 0; nf < 2; ++nf)
      #pragma unroll
      for (int i = 0; i < 9; ++i) zred[wv][nf*32 + l31][i] = zz[nf][i];
  }
  __syncthreads();
  for (int t = tid; t < 576; t += 256){
    int sm = t / 9, i = t - sm*9;
    float s = zred[0][sm][i] + zred[1][sm][i] + zred[2][sm][i] + zred[3][sm][i];
    qo[(size_t)(nb*64 + sm)*9 + i] = s;
  }
}

// ---------------- fc
__global__ void k_fc(const float* __restrict__ q, const float* __restrict__ fw,
                     const float* __restrict__ fb, float* __restrict__ out){
  int idx = blockIdx.x*256 + threadIdx.x;
  if (idx >= NB*5) return;
  int b = idx / 5, o = idx - b*5;
  const float* qr = q + (size_t)b*288;
  const float* wr = fw + (size_t)o*288;
  float s = 0.f;
  for (int j = 0; j < 288; ++j) s += qr[j]*wr[j];
  out[idx] = s + fb[o];
}

extern "C" void kernel_launch(void* const* d_in, const int* in_sizes, int n_in,
                              void* d_out, int out_size, void* d_ws, size_t ws_size,
                              hipStream_t stream){
  const float* x  = (const float*)d_in[0];
  const float* w1 = (const float*)d_in[1];
  const float* w2 = (const float*)d_in[2];
  const float* w3 = (const float*)d_in[3];
  const float* qw = (const float*)d_in[4];
  const float* fw = (const float*)d_in[5];
  const float* fb = (const float*)d_in[6];
  float* out = (float*)d_out;
  float* W = (float*)d_ws;

  float*  out1   = W + OFF_OUT1;
  ushort* a1h    = (ushort*)(W + OFF_A1H);
  ushort* a1l    = (ushort*)(W + OFF_A1L);
  ushort* w2ph   = (ushort*)(W + OFF_W2PH);
  ushort* w2pl   = (ushort*)(W + OFF_W2PL);
  ushort* w3ph   = (ushort*)(W + OFF_W3PH);
  ushort* w3pl   = (ushort*)(W + OFF_W3PL);
  ushort* uH     = (ushort*)(W + OFF_UH);
  ushort* uL     = (ushort*)(W + OFF_UL);
  float*  pool2raw = W + OFF_POOL2RAW;
  ushort* a2h    = (ushort*)(W + OFF_A2H);
  ushort* a2l    = (ushort*)(W + OFF_A2L);
  float*  featsraw = W + OFF_FEATSRAW;
  float*  qo     = W + OFF_QO;
  float*  part1  = W + OFF_PART1;
  float*  part2  = W + OFF_PART2;
  float*  part3  = W + OFF_PART3;
  float*  stats1 = W + OFF_STATS1;
  float*  stats2 = W + OFF_STATS2;
  float*  stats3 = W + OFF_STATS3;

  k_conv1s<<<NB, 256, 0, stream>>>(x, w1, out1, part1);
  k_stats_finP<<<16, 256, 0, stream>>>(part1, stats1, 16, NB*4, 1.f/((float)NB*H1*W1));
  k_bnelu1<<<NB*4, 256, 0, stream>>>(out1, stats1, a1h, a1l);
  k_cvtw<<<256, 256, 0, stream>>>(w2, w3, w2ph, w2pl, w3ph, w3pl);
  k_buildU<<<128, 256, 0, stream>>>(qw, uH, uL);
  k_conv2f5<0><<<NB, 320, 0, stream>>>(a1h, a1l, w2ph, w2pl, pool2raw, part2);
  k_conv2f5<1><<<NB, 320, 0, stream>>>(a1h, a1l, w2ph, w2pl, pool2raw, part2);
  k_stats_finP<<<32, 256, 0, stream>>>(part2, stats2, 32, NB*2, 1.f/((float)NB*H2*W2));
  k_bn2<<<NB*2, 256, 0, stream>>>(pool2raw, stats2, a2h, a2l);
  k_conv3f<<<NB/2, 256, 0, stream>>>(a2h, a2l, w3ph, w3pl, featsraw, part3);
  k_stats_finP<<<32, 256, 0, stream>>>(part3, stats3, 32, NB/2, 1.f/((float)NB*2*W3));
  k_qgemm<<<NB/2, 256, 0, stream>>>(featsraw, stats3, uH, uL, qo);
  k_fc<<<20, 256, 0, stream>>>(qo, fw, fb, out);
}

// Round 15
// 316.835 us; speedup vs baseline: 1.1247x; 1.1247x over previous
//
#include <hip/hip_runtime.h>
#include <math.h>

#define NB 1024
#define C1 16
#define H1 4
#define W1 153
#define WX 216
#define K1 64
#define C2 32
#define H2 4
#define W2 155
#define W192 192
#define PW2 38
#define C3 32
#define W3 38

typedef short short4v __attribute__((ext_vector_type(4)));
typedef short short8 __attribute__((ext_vector_type(8)));
typedef float f32x16 __attribute__((ext_vector_type(16)));

// ---- workspace float offsets
#define OFF_OUT1     0
#define OFF_A1H      10027008
#define OFF_A1L      16318464
#define OFF_W2PH     22609920
#define OFF_W2PL     22626304
#define OFF_W3PH     22642688
#define OFF_W3PL     22659072
#define OFF_UH       22675456
#define OFF_UL       22806528
#define OFF_POOL2RAW 22937600
#define OFF_A2H      25427968
#define OFF_A2L      27787264
#define OFF_FEATSRAW 30146560
#define OFF_QO       30441472
#define OFF_PART1    30736384
#define OFF_PART2    30867456
#define OFF_PART3    30998528
#define OFF_STATS1   31031296
#define OFF_STATS2   31031328
#define OFF_STATS3   31031392

__device__ __forceinline__ float eluf(float x){ return x > 0.f ? x : expm1f(x); }

__device__ __forceinline__ ushort bf16h(float x){
  unsigned u = __float_as_uint(x);
  unsigned r = u + 0x7fffu + ((u >> 16) & 1u);
  return (ushort)(r >> 16);
}
__device__ __forceinline__ float bf16f(ushort h){ return __uint_as_float(((unsigned)h) << 16); }

__device__ __forceinline__ short8 cat8(short4v a, short4v b){
  return __builtin_shufflevector(a, b, 0,1,2,3,4,5,6,7);
}

// ---------------- conv1 + fused BN stats partial
__global__ __launch_bounds__(256) void k_conv1s(const float* __restrict__ x,
                                                const float* __restrict__ w1,
                                                float* __restrict__ out1,
                                                float* __restrict__ part1){
  __shared__ float xr[4][WX];
  __shared__ float wl[C1*K1];
  int n = blockIdx.x, tid = threadIdx.x;
  for (int i = tid; i < 4*WX; i += 256) xr[i/WX][i%WX] = x[(size_t)n*4*WX + i];
  for (int i = tid; i < C1*K1; i += 256) wl[i] = w1[i];
  __syncthreads();
  int h = tid >> 6, lane = tid & 63;
  float acc[16][3];
  #pragma unroll
  for (int c = 0; c < 16; ++c){ acc[c][0]=0.f; acc[c][1]=0.f; acc[c][2]=0.f; }
  bool v2 = (lane + 128) < W1;
  for (int k = 0; k < 64; ++k){
    float x0 = xr[h][lane + k];
    float x1 = xr[h][lane + 64 + k];
    float x2 = v2 ? xr[h][lane + 128 + k] : 0.f;
    #pragma unroll
    for (int c = 0; c < 16; ++c){
      float wk = wl[c*64 + k];
      acc[c][0] += wk*x0; acc[c][1] += wk*x1; acc[c][2] += wk*x2;
    }
  }
  float ss[16], sq[16];
  #pragma unroll
  for (int c = 0; c < 16; ++c){
    float* ob = out1 + (((size_t)(n*16 + c)*4 + h))*W1;
    ob[lane] = acc[c][0];
    ob[lane + 64] = acc[c][1];
    if (v2) ob[lane + 128] = acc[c][2];
    ss[c] = acc[c][0] + acc[c][1] + acc[c][2];
    sq[c] = acc[c][0]*acc[c][0] + acc[c][1]*acc[c][1] + acc[c][2]*acc[c][2];
  }
  #pragma unroll
  for (int m = 1; m < 64; m <<= 1){
    #pragma unroll
    for (int c = 0; c < 16; ++c){ ss[c] += __shfl_xor(ss[c], m); sq[c] += __shfl_xor(sq[c], m); }
  }
  if (lane == 0){
    #pragma unroll
    for (int c = 0; c < 16; ++c){
      part1[((size_t)(n*4 + h)*16 + c)*2]     = ss[c];
      part1[((size_t)(n*4 + h)*16 + c)*2 + 1] = sq[c];
    }
  }
}

// ---------------- parallel stats finalize: grid = C blocks
__global__ __launch_bounds__(256) void k_stats_finP(const float* __restrict__ part,
                                                    float* __restrict__ stats,
                                                    int C, int nblk, float inv){
  __shared__ float rs[256], rq[256];
  int c = blockIdx.x;
  float s = 0.f, q = 0.f;
  for (int b = threadIdx.x; b < nblk; b += 256){
    s += part[((size_t)b*C + c)*2];
    q += part[((size_t)b*C + c)*2 + 1];
  }
  rs[threadIdx.x] = s; rq[threadIdx.x] = q; __syncthreads();
  for (int st = 128; st > 0; st >>= 1){
    if (threadIdx.x < st){ rs[threadIdx.x] += rs[threadIdx.x+st]; rq[threadIdx.x] += rq[threadIdx.x+st]; }
    __syncthreads();
  }
  if (threadIdx.x == 0){
    float mean = rs[0]*inv;
    float var  = rq[0]*inv - mean*mean;
    stats[c*2]   = mean;
    stats[c*2+1] = rsqrtf(var + 1e-5f);
  }
}

// ---------------- bnelu1: LDS-staged coalesced. block=(n,h). 8-granular ci swizzle.
__global__ __launch_bounds__(256) void k_bnelu1(const float* __restrict__ out1,
                                                const float* __restrict__ stats,
                                                ushort* __restrict__ a1h, ushort* __restrict__ a1l){
  __shared__ float xf[2448];   // 16ci x 153w
  __shared__ float st[32];
  int b = blockIdx.x;          // = n*4 + h
  int n = b >> 2, h = b & 3;
  int tid = threadIdx.x;
  if (tid < 32) st[tid] = stats[tid];
  for (int i = tid; i < 2448; i += 256){
    int ci = i / 153, w = i - ci*153;
    xf[i] = out1[((size_t)(n*16 + ci)*4 + h)*W1 + w];
  }
  __syncthreads();
  for (int i = tid; i < 3072; i += 256){
    int w = i >> 4, ci = i & 15;
    float v = 0.f;
    int ws = w - 16;
    if ((unsigned)ws < (unsigned)W1){
      float xx = xf[ci*153 + ws];
      v = eluf((xx - st[ci*2])*st[ci*2+1]);
    }
    int ciS = ci ^ (((w >> 2) & 1) << 3);   // 8-granular swizzle (matches conv2f b128 reads)
    size_t o = (size_t)b*3072 + w*16 + ciS;
    ushort hs = bf16h(v);
    a1h[o] = hs;
    a1l[o] = bf16h(v - bf16f(hs));
  }
}

// ---------------- weight convert+permute
__global__ void k_cvtw(const float* __restrict__ w2, const float* __restrict__ w3,
                       ushort* __restrict__ w2ph, ushort* __restrict__ w2pl,
                       ushort* __restrict__ w3ph, ushort* __restrict__ w3pl){
  int idx = blockIdx.x*256 + threadIdx.x;
  if (idx < 32768){
    int ci = idx & 15; int co = (idx >> 4) & 31; int rk = idx >> 9;
    int r = rk >> 5, kw = rk & 31;
    float v = w2[((size_t)(co*16 + ci)*2 + r)*32 + kw];
    ushort hs = bf16h(v); float hf = bf16f(hs);
    w2ph[idx] = hs; w2pl[idx] = bf16h(v - hf);
  } else {
    int j = idx - 32768;
    int ci = j & 31; int co = (j >> 5) & 31; int rk = j >> 10;
    int r = rk >> 2, kw = rk & 3;
    float v = w3[((size_t)(co*32 + ci)*8 + r)*4 + kw];
    ushort hs = bf16h(v); float hf = bf16f(hs);
    w3ph[j] = hs; w3pl[j] = bf16h(v - hf);
  }
}

// ---------------- fused conv2 v4 (best-measured 134us): block = (n, HG h-pair),
// 4 waves = PS position split, (256,4) => 16 waves/CU. b128 reads, k-slot map
// (l5,j)->l5*8+j on BOTH A and B, 8-granular XOR swizzle. Spills tolerated.
template<int HG, int PS>
__device__ __forceinline__ void conv2_body(const ushort* s_hi, const ushort* s_lo,
                                           const ushort* __restrict__ w2ph,
                                           const ushort* __restrict__ w2pl,
                                           float* __restrict__ pool2raw,
                                           float (*statW)[32][2],
                                           int n, int l31, int l5){
  constexpr int P0 = (PS == 0) ? 0 : (PS + 1);   // PS0:{0,1}, PS1:{2}, PS2:{3}, PS3:{4}
  constexpr int NP = (PS == 0) ? 2 : 1;
  constexpr int NR = (HG == 0) ? 3 : 2;          // staged rows (local j = 0..NR-1)
  int e8 = l5*8;

  f32x16 acc[2][NP];
  #pragma unroll
  for (int lh = 0; lh < 2; ++lh)
    #pragma unroll
    for (int p = 0; p < NP; ++p)
      #pragma unroll
      for (int e = 0; e < 16; ++e) acc[lh][p][e] = 0.f;

  for (int kw = 0; kw < 32; ++kw){
    short8 Ah[2], Al[2];
    #pragma unroll
    for (int r = 0; r < 2; ++r){
      int widx = ((r*32 + kw)*32 + l31)*16 + e8;
      Ah[r] = *(const short8*)(w2ph + widx);
      Al[r] = *(const short8*)(w2pl + widx);
    }
    #pragma unroll
    for (int j = 0; j < NR; ++j){
      int rb = j*3072;
      short8 bh[NP], bl[NP];
      #pragma unroll
      for (int p = 0; p < NP; ++p){
        int pos = (P0 + p)*32 + l31 + kw;
        int off = rb + pos*16 + (e8 ^ (((pos >> 2) & 1) << 3));
        bh[p] = *(const short8*)(s_hi + off);
        bl[p] = *(const short8*)(s_lo + off);
      }
      // combos (lh, r) with lh + r == j
      #pragma unroll
      for (int lh = 0; lh < 2; ++lh){
        #pragma unroll
        for (int r = 0; r < 2; ++r){
          if (lh + r != j) continue;
          #pragma unroll
          for (int p = 0; p < NP; ++p){
            acc[lh][p] = __builtin_amdgcn_mfma_f32_32x32x16_bf16(Ah[r], bh[p], acc[lh][p], 0, 0, 0);
            acc[lh][p] = __builtin_amdgcn_mfma_f32_32x32x16_bf16(Ah[r], bl[p], acc[lh][p], 0, 0, 0);
            acc[lh][p] = __builtin_amdgcn_mfma_f32_32x32x16_bf16(Al[r], bh[p], acc[lh][p], 0, 0, 0);
          }
        }
      }
    }
  }

  // ---- stats partial (mask pos>=155); C/D map col=l31, row co=(e&3)+8*(e>>2)+4*l5
  {
    float sreg[16], qreg[16];
    #pragma unroll
    for (int e = 0; e < 16; ++e){ sreg[e] = 0.f; qreg[e] = 0.f; }
    #pragma unroll
    for (int lh = 0; lh < 2; ++lh){
      #pragma unroll
      for (int p = 0; p < NP; ++p){
        bool pv = ((P0 + p) < 4) || (l31 < 27);
        #pragma unroll
        for (int e = 0; e < 16; ++e){
          float v = pv ? acc[lh][p][e] : 0.f;
          sreg[e] += v; qreg[e] += v*v;
        }
      }
    }
    #pragma unroll
    for (int m = 1; m < 32; m <<= 1){
      #pragma unroll
      for (int e = 0; e < 16; ++e){
        sreg[e] += __shfl_xor(sreg[e], m);
        qreg[e] += __shfl_xor(qreg[e], m);
      }
    }
    if (l31 == 0){
      #pragma unroll
      for (int e = 0; e < 16; ++e){
        int co = (e & 3) + ((e >> 2) << 3) + (l5 << 2);
        statW[PS][co][0] = sreg[e];
        statW[PS][co][1] = qreg[e];
      }
    }
  }
  // ---- in-register cross-h max + quad pool, direct global write
  #pragma unroll
  for (int p = 0; p < NP; ++p){
    #pragma unroll
    for (int e = 0; e < 16; ++e){
      float m0 = fmaxf(acc[0][p][e], acc[1][p][e]);
      float v1 = fmaxf(m0, __shfl_xor(m0, 1));
      float v2m = fmaxf(v1, __shfl_xor(v1, 2));
      int pw = (P0 + p)*8 + (l31 >> 2);
      if ((l31 & 3) == 0 && pw < PW2){
        int co = (e & 3) + ((e >> 2) << 3) + (l5 << 2);
        pool2raw[(((size_t)n*2 + HG)*32 + co)*PW2 + pw] = v2m;
      }
    }
  }
}

__global__ __launch_bounds__(256, 4) void k_conv2f(const ushort* __restrict__ a1h,
                                                   const ushort* __restrict__ a1l,
                                                   const ushort* __restrict__ w2ph,
                                                   const ushort* __restrict__ w2pl,
                                                   float* __restrict__ pool2raw,
                                                   float* __restrict__ part2){
  __shared__ __align__(16) ushort s_hi[3*3072];
  __shared__ __align__(16) ushort s_lo[3*3072];
  __shared__ float statW[4][32][2];
  int b = blockIdx.x;          // 2048: (n, HG)
  int n = b >> 1, HG = b & 1;
  int tid = threadIdx.x;
  int nrows = HG ? 2 : 3;
  {
    const float4* gh = (const float4*)(a1h + ((size_t)n*4 + 2*HG)*3072);
    const float4* gl = (const float4*)(a1l + ((size_t)n*4 + 2*HG)*3072);
    float4* dh = (float4*)s_hi;
    float4* dl = (float4*)s_lo;
    int cnt = nrows*384;
    for (int i = tid; i < cnt; i += 256){ dh[i] = gh[i]; dl[i] = gl[i]; }
  }
  __syncthreads();
  int wv = tid >> 6, lane = tid & 63;
  int l5 = lane >> 5, l31 = lane & 31;
  int ps = (wv + b) & 3;       // role permute for SIMD balance
  if (HG == 0){
    switch (ps){
      case 0: conv2_body<0,0>(s_hi, s_lo, w2ph, w2pl, pool2raw, statW, n, l31, l5); break;
      case 1: conv2_body<0,1>(s_hi, s_lo, w2ph, w2pl, pool2raw, statW, n, l31, l5); break;
      case 2: conv2_body<0,2>(s_hi, s_lo, w2ph, w2pl, pool2raw, statW, n, l31, l5); break;
      default: conv2_body<0,3>(s_hi, s_lo, w2ph, w2pl, pool2raw, statW, n, l31, l5); break;
    }
  } else {
    switch (ps){
      case 0: conv2_body<1,0>(s_hi, s_lo, w2ph, w2pl, pool2raw, statW, n, l31, l5); break;
      case 1: conv2_body<1,1>(s_hi, s_lo, w2ph, w2pl, pool2raw, statW, n, l31, l5); break;
      case 2: conv2_body<1,2>(s_hi, s_lo, w2ph, w2pl, pool2raw, statW, n, l31, l5); break;
      default: conv2_body<1,3>(s_hi, s_lo, w2ph, w2pl, pool2raw, statW, n, l31, l5); break;
    }
  }
  __syncthreads();
  if (tid < 32){
    float s = statW[0][tid][0] + statW[1][tid][0] + statW[2][tid][0] + statW[3][tid][0];
    float q = statW[0][tid][1] + statW[1][tid][1] + statW[2][tid][1] + statW[3][tid][1];
    part2[(((size_t)n*2 + HG)*32 + tid)*2]     = s;
    part2[(((size_t)n*2 + HG)*32 + tid)*2 + 1] = q;
  }
}

// ---------------- bn2: LDS-staged coalesced. block=(n,hr)
__global__ __launch_bounds__(256) void k_bn2(const float* __restrict__ pool2raw,
                                             const float* __restrict__ stats,
                                             ushort* __restrict__ a2h, ushort* __restrict__ a2l){
  __shared__ float xf[1216];   // 32ci x 38pw
  __shared__ float st[64];
  int b = blockIdx.x;          // = n*2 + hr, 2048
  int tid = threadIdx.x;
  if (tid < 64) st[tid] = stats[tid];
  for (int i = tid; i < 1216; i += 256) xf[i] = pool2raw[(size_t)b*1216 + i];
  __syncthreads();
  for (int i = tid; i < 2304; i += 256){
    int w = i >> 5, ci = i & 31;
    float v = 0.f;
    int pw = w - 2;
    if ((unsigned)pw < (unsigned)PW2)
      v = eluf((xf[ci*38 + pw] - st[ci*2])*st[ci*2+1]);
    int ciS = ci ^ (((w >> 1) & 7) << 2);
    size_t o = (size_t)b*2304 + w*32 + ciS;
    ushort hs = bf16h(v);
    a2h[o] = hs; a2l[o] = bf16h(v - bf16f(hs));
  }
}

// ---------------- fused conv3 (MFMA 3-term bf16) + stats partial + maxpool(2,4)
__global__ __launch_bounds__(256, 2) void k_conv3f(const ushort* __restrict__ a2h,
                                                   const ushort* __restrict__ a2l,
                                                   const ushort* __restrict__ w3ph,
                                                   const ushort* __restrict__ w3pl,
                                                   float* __restrict__ featsraw,
                                                   float* __restrict__ part3){
  __shared__ __align__(16) ushort s3h[9216];
  __shared__ __align__(16) ushort s3l[9216];
  __shared__ float poolL3[4][32][12];
  __shared__ float statL3[4][32][2];
  int nb = blockIdx.x;
  int tid = threadIdx.x;
  {
    const float4* gh = (const float4*)(a2h + (size_t)nb*9216);
    const float4* gl = (const float4*)(a2l + (size_t)nb*9216);
    float4* dh = (float4*)s3h;
    float4* dl = (float4*)s3l;
    for (int i = tid; i < 1152; i += 256){ dh[i] = gh[i]; dl[i] = gl[i]; }
  }
  __syncthreads();
  int wave = tid >> 6, lane = tid & 63;
  int nh = wave >> 1, h = wave & 1;
  int l5 = lane >> 5, l31 = lane & 31;

  f32x16 acc[2];
  #pragma unroll
  for (int p = 0; p < 2; ++p)
    #pragma unroll
    for (int e = 0; e < 16; ++e) acc[p][e] = 0.f;

  #pragma unroll
  for (int ri = 0; ri < 2; ++ri){
    int r = (h == 0) ? (4 + ri) : (3 + ri);
    int rbase = (nh*2 + ri)*72*32;
    #pragma unroll
    for (int kw = 0; kw < 4; ++kw){
      #pragma unroll
      for (int ch = 0; ch < 2; ++ch){
        int widx = ((r*4 + kw)*32 + l31)*32 + ch*16 + l5*4;
        short8 Ah = cat8(*(const short4v*)(w3ph + widx), *(const short4v*)(w3ph + widx + 8));
        short8 Al = cat8(*(const short4v*)(w3pl + widx), *(const short4v*)(w3pl + widx + 8));
        short8 Bh[2], Bl[2];
        #pragma unroll
        for (int p = 0; p < 2; ++p){
          int pos = p*32 + l31 + kw;
          int sw = ((pos >> 1) & 7) << 2;
          int s0 = ch*16 + l5*4;
          int off0 = rbase + pos*32 + (s0 ^ sw);
          int off1 = rbase + pos*32 + ((s0 + 8) ^ sw);
          Bh[p] = cat8(*(const short4v*)(s3h + off0), *(const short4v*)(s3h + off1));
          Bl[p] = cat8(*(const short4v*)(s3l + off0), *(const short4v*)(s3l + off1));
        }
        #pragma unroll
        for (int p = 0; p < 2; ++p) acc[p] = __builtin_amdgcn_mfma_f32_32x32x16_bf16(Ah, Bh[p], acc[p], 0, 0, 0);
        #pragma unroll
        for (int p = 0; p < 2; ++p) acc[p] = __builtin_amdgcn_mfma_f32_32x32x16_bf16(Ah, Bl[p], acc[p], 0, 0, 0);
        #pragma unroll
        for (int p = 0; p < 2; ++p) acc[p] = __builtin_amdgcn_mfma_f32_32x32x16_bf16(Al, Bh[p], acc[p], 0, 0, 0);
      }
    }
  }

  {
    float sreg[16], qreg[16];
    #pragma unroll
    for (int e = 0; e < 16; ++e){ sreg[e] = 0.f; qreg[e] = 0.f; }
    #pragma unroll
    for (int p = 0; p < 2; ++p){
      bool pv = (p == 0) || (l31 < 6);
      #pragma unroll
      for (int e = 0; e < 16; ++e){
        float v = pv ? acc[p][e] : 0.f;
        sreg[e] += v; qreg[e] += v*v;
      }
    }
    #pragma unroll
    for (int m = 1; m < 32; m <<= 1){
      #pragma unroll
      for (int e = 0; e < 16; ++e){
        sreg[e] += __shfl_xor(sreg[e], m);
        qreg[e] += __shfl_xor(qreg[e], m);
      }
    }
    if (l31 == 0){
      #pragma unroll
      for (int e = 0; e < 16; ++e){
        int co = (e & 3) + ((e >> 2) << 3) + (l5 << 2);
        statL3[wave][co][0] = sreg[e];
        statL3[wave][co][1] = qreg[e];
      }
    }
  }
  #pragma unroll
  for (int p = 0; p < 2; ++p){
    #pragma unroll
    for (int e = 0; e < 16; ++e){
      float v = acc[p][e];
      float v1 = fmaxf(v, __shfl_xor(v, 1));
      float v2m = fmaxf(v1, __shfl_xor(v1, 2));
      int pw = p*8 + (l31 >> 2);
      if ((l31 & 3) == 0 && pw < 9){
        int co = (e & 3) + ((e >> 2) << 3) + (l5 << 2);
        poolL3[wave][co][pw] = v2m;
      }
    }
  }
  __syncthreads();
  for (int i = tid; i < 2*32*9; i += 256){
    int pw = i % 9; int t = i / 9; int co = t & 31; int nh2 = t >> 5;
    float v = fmaxf(poolL3[nh2*2][co][pw], poolL3[nh2*2+1][co][pw]);
    featsraw[((size_t)(nb*2 + nh2)*32 + co)*9 + pw] = v;
  }
  if (tid < 32){
    float s = 0.f, q = 0.f;
    #pragma unroll
    for (int wv = 0; wv < 4; ++wv){ s += statL3[wv][tid][0]; q += statL3[wv][tid][1]; }
    part3[((size_t)nb*32 + tid)*2]     = s;
    part3[((size_t)nb*32 + tid)*2 + 1] = q;
  }
}

// ---------------- build U (512x512) by running the fixed circuit on basis states
__global__ __launch_bounds__(256) void k_buildU(const float* __restrict__ qw,
                                                ushort* __restrict__ Uh, ushort* __restrict__ Ul){
  __shared__ float wt[36][2];
  int tid = threadIdx.x;
  if (tid < 36){ float s, c; sincosf(qw[tid]*0.5f, &s, &c); wt[tid][0] = c; wt[tid][1] = s; }
  __syncthreads();
  int wid = tid >> 6, lane = tid & 63;
  int k = blockIdx.x*4 + wid;
  float v[8];
  #pragma unroll
  for (int r = 0; r < 8; ++r) v[r] = (lane*8 + r == k) ? 1.f : 0.f;

  for (int j = 0; j < 4; ++j){
    #pragma unroll
    for (int i = 0; i < 5; ++i){
      int cm = 32>>i, tm = 16>>i;
      bool flip = (lane & cm) != 0;
      #pragma unroll
      for (int r = 0; r < 8; ++r){
        float w = __shfl_xor(v[r], tm);
        v[r] = flip ? w : v[r];
      }
    }
    { bool flip = (lane & 1) != 0;
      #pragma unroll
      for (int r = 0; r < 4; ++r){ float a = v[r], bb = v[r+4]; v[r] = flip?bb:a; v[r+4] = flip?a:bb; } }
    { float t = v[4]; v[4] = v[6]; v[6] = t; t = v[5]; v[5] = v[7]; v[7] = t; }
    { float t = v[2]; v[2] = v[3]; v[3] = t; t = v[6]; v[6] = v[7]; v[7] = t; }
    #pragma unroll
    for (int r = 1; r < 8; r += 2) v[r] = __shfl_xor(v[r], 32);

    #pragma unroll
    for (int i = 0; i < 6; ++i){
      float c = wt[j*9+i][0], s = wt[j*9+i][1];
      int m = 32>>i;
      float sg = (lane & m) ? s : -s;
      #pragma unroll
      for (int r = 0; r < 8; ++r){
        float w = __shfl_xor(v[r], m);
        v[r] = c*v[r] + sg*w;
      }
    }
    { float c = wt[j*9+6][0], s = wt[j*9+6][1];
      #pragma unroll
      for (int r = 0; r < 4; ++r){ float a = v[r], bb = v[r+4]; v[r] = c*a - s*bb; v[r+4] = s*a + c*bb; } }
    { float c = wt[j*9+7][0], s = wt[j*9+7][1]; float a, bb;
      a=v[0]; bb=v[2]; v[0]=c*a-s*bb; v[2]=s*a+c*bb;
      a=v[1]; bb=v[3]; v[1]=c*a-s*bb; v[3]=s*a+c*bb;
      a=v[4]; bb=v[6]; v[4]=c*a-s*bb; v[6]=s*a+c*bb;
      a=v[5]; bb=v[7]; v[5]=c*a-s*bb; v[7]=s*a+c*bb; }
    { float c = wt[j*9+8][0], s = wt[j*9+8][1]; float a, bb;
      a=v[0]; bb=v[1]; v[0]=c*a-s*bb; v[1]=s*a+c*bb;
      a=v[2]; bb=v[3]; v[2]=c*a-s*bb; v[3]=s*a+c*bb;
      a=v[4]; bb=v[5]; v[4]=c*a-s*bb; v[5]=s*a+c*bb;
      a=v[6]; bb=v[7]; v[6]=c*a-s*bb; v[7]=s*a+c*bb; }
  }
  #pragma unroll
  for (int r = 0; r < 8; ++r){
    int s = lane*8 + r;
    int mf = s >> 5, r31 = s & 31;
    int addr = (((k >> 4)*16 + mf)*32 + r31)*16 + (k & 15);
    float f = v[r];
    ushort hi = bf16h(f);
    Uh[addr] = hi;
    Ul[addr] = bf16h(f - bf16f(hi));
  }
}

// ---------------- quantum GEMM: state = U @ b(sample), fused BN+ELU + <Z> epilogue
__global__ __launch_bounds__(256, 1) void k_qgemm(const float* __restrict__ featsraw,
                                                  const float* __restrict__ stats,
                                                  const ushort* __restrict__ Uh,
                                                  const ushort* __restrict__ Ul,
                                                  float* __restrict__ qo){
  __shared__ __align__(16) ushort BhL[32768];
  __shared__ __align__(16) ushort BlL[32768];
  __shared__ float angL[576];
  __shared__ float zred[4][64][9];
  int nb = blockIdx.x;
  int tid = threadIdx.x;
  for (int t = tid; t < 576; t += 256){
    float vr = featsraw[(size_t)nb*576 + t];
    int c = (t/9) & 31;
    angL[t] = 0.5f * eluf((vr - stats[c*2])*stats[c*2+1]);
  }
  __syncthreads();
  {
    int sm = tid >> 2, q = tid & 3;
    float tc[9], ts[9];
    #pragma unroll
    for (int i = 0; i < 9; ++i) sincosf(angL[sm*9 + i], &ts[i], &tc[i]);
    float Pc = ((q & 2) ? ts[0] : tc[0]) * ((q & 1) ? ts[1] : tc[1]);
    int swz = (sm >> 2) & 3;
    short4v* bh4 = (short4v*)BhL;
    short4v* bl4 = (short4v*)BlL;
    int j = 0;
    #pragma unroll
    for (int b2 = 0; b2 < 2; ++b2){ float p2 = Pc*(b2 ? ts[2] : tc[2]);
    #pragma unroll
    for (int b3 = 0; b3 < 2; ++b3){ float p3 = p2*(b3 ? ts[3] : tc[3]);
    #pragma unroll
    for (int b4 = 0; b4 < 2; ++b4){ float p4 = p3*(b4 ? ts[4] : tc[4]);
    #pragma unroll
    for (int b5 = 0; b5 < 2; ++b5){ float p5 = p4*(b5 ? ts[5] : tc[5]);
    #pragma unroll
    for (int b6 = 0; b6 < 2; ++b6){ float p6 = p5*(b6 ? ts[6] : tc[6]);
      float a0 = p6*tc[7]*tc[8];
      float a1 = p6*tc[7]*ts[8];
      float a2 = p6*ts[7]*tc[8];
      float a3 = p6*ts[7]*ts[8];
      ushort h0 = bf16h(a0), h1 = bf16h(a1), h2 = bf16h(a2), h3 = bf16h(a3);
      short4v hv; hv[0]=(short)h0; hv[1]=(short)h1; hv[2]=(short)h2; hv[3]=(short)h3;
      short4v lv; lv[0]=(short)bf16h(a0 - bf16f(h0)); lv[1]=(short)bf16h(a1 - bf16f(h1));
                  lv[2]=(short)bf16h(a2 - bf16f(h2)); lv[3]=(short)bf16h(a3 - bf16f(h3));
      int kk = q*128 + j;
      int kstep = kk >> 4;
      int g = (kk >> 2) & 3;
      int idx4 = (kstep*64 + sm)*4 + (g ^ swz);
      bh4[idx4] = hv; bl4[idx4] = lv;
      j += 4;
    }}}}}
  }
  __syncthreads();
  int wv = tid >> 6, lane = tid & 63, l5 = lane >> 5, l31 = lane & 31;
  f32x16 acc[4][2];
  #pragma unroll
  for (int jj = 0; jj < 4; ++jj)
    #pragma unroll
    for (int nf = 0; nf < 2; ++nf)
      #pragma unroll
      for (int e = 0; e < 16; ++e) acc[jj][nf][e] = 0.f;

  for (int kstep = 0; kstep < 32; ++kstep){
    short8 Bh[2], Bl[2];
    #pragma unroll
    for (int nf = 0; nf < 2; ++nf){
      int sm = nf*32 + l31;
      int base = (kstep*64 + sm)*16;
      int sz = ((sm >> 2) & 3) << 2;
      int e0 = (l5*4) ^ sz;
      int e1 = (l5*4 + 8) ^ sz;
      Bh[nf] = cat8(*(const short4v*)(BhL + base + e0), *(const short4v*)(BhL + base + e1));
      Bl[nf] = cat8(*(const short4v*)(BlL + base + e0), *(const short4v*)(BlL + base + e1));
    }
    #pragma unroll
    for (int jj = 0; jj < 4; ++jj){
      int mf = wv*4 + jj;
      const ushort* ah = Uh + ((kstep*16 + mf)*32 + l31)*16 + l5*4;
      const ushort* al = Ul + ((kstep*16 + mf)*32 + l31)*16 + l5*4;
      short8 Ah = cat8(*(const short4v*)ah, *(const short4v*)(ah + 8));
      short8 Al = cat8(*(const short4v*)al, *(const short4v*)(al + 8));
      acc[jj][0] = __builtin_amdgcn_mfma_f32_32x32x16_bf16(Ah, Bh[0], acc[jj][0], 0, 0, 0);
      acc[jj][1] = __builtin_amdgcn_mfma_f32_32x32x16_bf16(Ah, Bh[1], acc[jj][1], 0, 0, 0);
      acc[jj][0] = __builtin_amdgcn_mfma_f32_32x32x16_bf16(Ah, Bl[0], acc[jj][0], 0, 0, 0);
      acc[jj][1] = __builtin_amdgcn_mfma_f32_32x32x16_bf16(Ah, Bl[1], acc[jj][1], 0, 0, 0);
      acc[jj][0] = __builtin_amdgcn_mfma_f32_32x32x16_bf16(Al, Bh[0], acc[jj][0], 0, 0, 0);
      acc[jj][1] = __builtin_amdgcn_mfma_f32_32x32x16_bf16(Al, Bh[1], acc[jj][1], 0, 0, 0);
    }
  }
  float zz[2][9];
  #pragma unroll
  for (int nf = 0; nf < 2; ++nf)
    #pragma unroll
    for (int i = 0; i < 9; ++i) zz[nf][i] = 0.f;
  #pragma unroll
  for (int jj = 0; jj < 4; ++jj){
    int mf = wv*4 + jj;
    float sg0 = (mf & 8) ? -1.f : 1.f;
    float sg1 = (mf & 4) ? -1.f : 1.f;
    float sg2 = (mf & 2) ? -1.f : 1.f;
    float sg3 = (mf & 1) ? -1.f : 1.f;
    #pragma unroll
    for (int nf = 0; nf < 2; ++nf){
      float psum = 0.f, z4 = 0.f, z5 = 0.f, z7 = 0.f, z8 = 0.f;
      #pragma unroll
      for (int e = 0; e < 16; ++e){
        float qv = acc[jj][nf][e]*acc[jj][nf][e];
        psum += qv;
        z4 += ((e >> 3) & 1) ? -qv : qv;
        z5 += ((e >> 2) & 1) ? -qv : qv;
        z7 += ((e >> 1) & 1) ? -qv : qv;
        z8 += (e & 1) ? -qv : qv;
      }
      zz[nf][0] += sg0*psum; zz[nf][1] += sg1*psum;
      zz[nf][2] += sg2*psum; zz[nf][3] += sg3*psum;
      zz[nf][4] += z4; zz[nf][5] += z5;
      zz[nf][6] += l5 ? -psum : psum;
      zz[nf][7] += z7; zz[nf][8] += z8;
    }
  }
  #pragma unroll
  for (int nf = 0; nf < 2; ++nf)
    #pragma unroll
    for (int i = 0; i < 9; ++i) zz[nf][i] += __shfl_xor(zz[nf][i], 32);
  if (l5 == 0){
    #pragma unroll
    for (int nf = 0; nf < 2; ++nf)
      #pragma unroll
      for (int i = 0; i < 9; ++i) zred[wv][nf*32 + l31][i] = zz[nf][i];
  }
  __syncthreads();
  for (int t = tid; t < 576; t += 256){
    int sm = t / 9, i = t - sm*9;
    float s = zred[0][sm][i] + zred[1][sm][i] + zred[2][sm][i] + zred[3][sm][i];
    qo[(size_t)(nb*64 + sm)*9 + i] = s;
  }
}

// ---------------- fc
__global__ void k_fc(const float* __restrict__ q, const float* __restrict__ fw,
                     const float* __restrict__ fb, float* __restrict__ out){
  int idx = blockIdx.x*256 + threadIdx.x;
  if (idx >= NB*5) return;
  int b = idx / 5, o = idx - b*5;
  const float* qr = q + (size_t)b*288;
  const float* wr = fw + (size_t)o*288;
  float s = 0.f;
  for (int j = 0; j < 288; ++j) s += qr[j]*wr[j];
  out[idx] = s + fb[o];
}

extern "C" void kernel_launch(void* const* d_in, const int* in_sizes, int n_in,
                              void* d_out, int out_size, void* d_ws, size_t ws_size,
                              hipStream_t stream){
  const float* x  = (const float*)d_in[0];
  const float* w1 = (const float*)d_in[1];
  const float* w2 = (const float*)d_in[2];
  const float* w3 = (const float*)d_in[3];
  const float* qw = (const float*)d_in[4];
  const float* fw = (const float*)d_in[5];
  const float* fb = (const float*)d_in[6];
  float* out = (float*)d_out;
  float* W = (float*)d_ws;

  float*  out1   = W + OFF_OUT1;
  ushort* a1h    = (ushort*)(W + OFF_A1H);
  ushort* a1l    = (ushort*)(W + OFF_A1L);
  ushort* w2ph   = (ushort*)(W + OFF_W2PH);
  ushort* w2pl   = (ushort*)(W + OFF_W2PL);
  ushort* w3ph   = (ushort*)(W + OFF_W3PH);
  ushort* w3pl   = (ushort*)(W + OFF_W3PL);
  ushort* uH     = (ushort*)(W + OFF_UH);
  ushort* uL     = (ushort*)(W + OFF_UL);
  float*  pool2raw = W + OFF_POOL2RAW;
  ushort* a2h    = (ushort*)(W + OFF_A2H);
  ushort* a2l    = (ushort*)(W + OFF_A2L);
  float*  featsraw = W + OFF_FEATSRAW;
  float*  qo     = W + OFF_QO;
  float*  part1  = W + OFF_PART1;
  float*  part2  = W + OFF_PART2;
  float*  part3  = W + OFF_PART3;
  float*  stats1 = W + OFF_STATS1;
  float*  stats2 = W + OFF_STATS2;
  float*  stats3 = W + OFF_STATS3;

  k_conv1s<<<NB, 256, 0, stream>>>(x, w1, out1, part1);
  k_stats_finP<<<16, 256, 0, stream>>>(part1, stats1, 16, NB*4, 1.f/((float)NB*H1*W1));
  k_bnelu1<<<NB*4, 256, 0, stream>>>(out1, stats1, a1h, a1l);
  k_cvtw<<<256, 256, 0, stream>>>(w2, w3, w2ph, w2pl, w3ph, w3pl);
  k_buildU<<<128, 256, 0, stream>>>(qw, uH, uL);
  k_conv2f<<<NB*2, 256, 0, stream>>>(a1h, a1l, w2ph, w2pl, pool2raw, part2);
  k_stats_finP<<<32, 256, 0, stream>>>(part2, stats2, 32, NB*2, 1.f/((float)NB*H2*W2));
  k_bn2<<<NB*2, 256, 0, stream>>>(pool2raw, stats2, a2h, a2l);
  k_conv3f<<<NB/2, 256, 0, stream>>>(a2h, a2l, w3ph, w3pl, featsraw, part3);
  k_stats_finP<<<32, 256, 0, stream>>>(part3, stats3, 32, NB/2, 1.f/((float)NB*2*W3));
  k_qgemm<<<NB/2, 256, 0, stream>>>(featsraw, stats3, uH, uL, qo);
  k_fc<<<20, 256, 0, stream>>>(qo, fw, fb, out);
}